// Round 3
// baseline (192.877 us; speedup 1.0000x reference)
//
#include <hip/hip_runtime.h>

typedef __bf16 bf16x8 __attribute__((ext_vector_type(8)));
typedef __bf16 bf16x4 __attribute__((ext_vector_type(4)));
typedef float  f32x4  __attribute__((ext_vector_type(4)));

__device__ __forceinline__ bf16x8 pack8(float4 a, float4 b) {
    bf16x8 r;
    r[0] = (__bf16)a.x; r[1] = (__bf16)a.y; r[2] = (__bf16)a.z; r[3] = (__bf16)a.w;
    r[4] = (__bf16)b.x; r[5] = (__bf16)b.y; r[6] = (__bf16)b.z; r[7] = (__bf16)b.w;
    return r;
}

// ---------------- Pass 1: merged projection GEMMs ----------------
// For each grid i: P_i (M_i,128) bf16 = A_i (M_i,K_i) f32 @ lin_w[:, off_i:off_i+K_i]^T
// lin_w is (128,448) row-major. One kernel, blocks partitioned per grid.
// M-tile = 128 rows, N = 128 (full), K-step = 32. 4 waves: 2 row-tiles x 8 col-tiles.
// Blocks whose 128-row range touches no needed t-slice (per coor_t) exit early:
// tmix only reads t-slices i0/i1 of the 24 (n,t) samples. 576 rows per t-slice
// (144 nodes x K_PROD=4) for ALL grids; a block spans at most 2 slices.
__global__ __launch_bounds__(256)
void proj_gemm_all(const float* __restrict__ g0, const float* __restrict__ g1,
                   const float* __restrict__ g2, const float* __restrict__ W,
                   const float* __restrict__ coor_t,
                   __bf16* __restrict__ P0, __bf16* __restrict__ P1,
                   __bf16* __restrict__ P2)
{
    __shared__ __bf16 As[128][40];   // [row][k]  pad 32->40 to spread banks
    __shared__ __bf16 Bs[128][40];   // [col][k]  (B^T layout so frag reads are contiguous)

    const int b = blockIdx.x;
    const float* A; __bf16* P; int K, w_off, m0, Tg;
    if (b < 540)      { A = g0; P = P0; K = 64;  w_off = 0;   m0 = b * 128;         Tg = 120; }
    else if (b < 810) { A = g1; P = P1; K = 128; w_off = 64;  m0 = (b - 540) * 128; Tg = 60;  }
    else              { A = g2; P = P2; K = 256; w_off = 192; m0 = (b - 810) * 128; Tg = 30;  }

    // dead t-slice early-exit (uniform across block; same math as tmix's addg)
    {
        const int t_lo = m0 / 576;
        const int t_hi = (m0 + 127) / 576;
        bool need = false;
        for (int nt = 0; nt < 24; nt++) {
            float c  = coor_t[nt];
            float x0 = fminf(fmaxf(floorf((c + 1.0f) * 0.5f * (float)(Tg - 1)), 0.0f),
                             (float)(Tg - 1));
            int i0 = (int)x0;
            int i1 = (i0 + 1 < Tg - 1) ? (i0 + 1) : (Tg - 1);
            if (i0 == t_lo || i0 == t_hi || i1 == t_lo || i1 == t_hi) { need = true; break; }
        }
        if (!need) return;
    }

    const int tid  = threadIdx.x;
    const int wid  = tid >> 6;
    const int lane = tid & 63;
    const int lrow = lane & 15;
    const int lk   = (lane >> 4) * 8;

    f32x4 acc[2][8];
#pragma unroll
    for (int rt = 0; rt < 2; rt++)
#pragma unroll
        for (int ct = 0; ct < 8; ct++) acc[rt][ct] = f32x4{0.f, 0.f, 0.f, 0.f};

    const int srow = tid >> 1;       // 0..127
    const int half = tid & 1;        // two 16-float segments per 32-float row chunk

    for (int k0 = 0; k0 < K; k0 += 32) {
        // stage A tile: rows m0..m0+127, k = k0..k0+31  (f32 -> bf16)
        {
            const float4* src = (const float4*)(A + (size_t)(m0 + srow) * K + k0 + half * 16);
            float4 f0 = src[0], f1 = src[1], f2 = src[2], f3 = src[3];
            *(bf16x8*)&As[srow][half * 16 + 0] = pack8(f0, f1);
            *(bf16x8*)&As[srow][half * 16 + 8] = pack8(f2, f3);
        }
        // stage B tile: Bs[col][k] = lin_w[col][w_off + k0 + k]  (coalesced)
        {
            const float4* src = (const float4*)(W + (size_t)srow * 448 + w_off + k0 + half * 16);
            float4 f0 = src[0], f1 = src[1], f2 = src[2], f3 = src[3];
            *(bf16x8*)&Bs[srow][half * 16 + 0] = pack8(f0, f1);
            *(bf16x8*)&Bs[srow][half * 16 + 8] = pack8(f2, f3);
        }
        __syncthreads();

        bf16x8 a[2], bfrag[8];
#pragma unroll
        for (int rt = 0; rt < 2; rt++)
            a[rt] = *(const bf16x8*)&As[wid * 32 + rt * 16 + lrow][lk];
#pragma unroll
        for (int ct = 0; ct < 8; ct++)
            bfrag[ct] = *(const bf16x8*)&Bs[ct * 16 + lrow][lk];
#pragma unroll
        for (int rt = 0; rt < 2; rt++)
#pragma unroll
            for (int ct = 0; ct < 8; ct++)
                acc[rt][ct] = __builtin_amdgcn_mfma_f32_16x16x32_bf16(a[rt], bfrag[ct], acc[rt][ct], 0, 0, 0);
        __syncthreads();
    }

    // epilogue: D layout col = lane&15, row = (lane>>4)*4 + j  [verified m89/m91]
#pragma unroll
    for (int rt = 0; rt < 2; rt++) {
        const int r0 = m0 + wid * 32 + rt * 16 + (lane >> 4) * 4;
#pragma unroll
        for (int ct = 0; ct < 8; ct++) {
            const int col = ct * 16 + lrow;
#pragma unroll
            for (int j = 0; j < 4; j++)
                P[(size_t)(r0 + j) * 128 + col] = (__bf16)acc[rt][ct][j];
        }
    }
}

// ---------------- Pass 2: t-interp + sum over grids ----------------
__device__ __forceinline__ void addg(const bf16x4* __restrict__ P, int Tg, float c,
                                     int hw, int kc4, float* acc)
{
    float x  = (c + 1.0f) * 0.5f * (float)(Tg - 1);
    float x0 = fminf(fmaxf(floorf(x), 0.0f), (float)(Tg - 1));
    int   i0 = (int)x0;
    int   i1 = (i0 + 1 < Tg - 1) ? (i0 + 1) : (Tg - 1);
    float f  = x - x0;
    bf16x4 lo = P[(i0 * 144 + hw) * 128 + kc4];
    bf16x4 hi = P[(i1 * 144 + hw) * 128 + kc4];
    float omf = 1.0f - f;
#pragma unroll
    for (int j = 0; j < 4; j++)
        acc[j] += (float)lo[j] * omf + (float)hi[j] * f;
}

__global__ __launch_bounds__(256)
void tmix(const bf16x4* __restrict__ P0, const bf16x4* __restrict__ P1,
          const bf16x4* __restrict__ P2, const float* __restrict__ coor_t,
          bf16x4* __restrict__ G)
{
    int v   = blockIdx.x * 256 + threadIdx.x;   // enumerates [nt][h][w][kc4]
    int kc4 = v & 127;
    int w   = (v >> 7) & 15;
    int r   = v >> 11;
    int h   = r % 9;
    int nt  = r / 9;                            // n*12 + t, < 24
    float c = coor_t[nt];
    int  hw = h * 16 + w;

    float acc[4] = {0.f, 0.f, 0.f, 0.f};
    addg(P0, 120, c, hw, kc4, acc);
    addg(P1,  60, c, hw, kc4, acc);
    addg(P2,  30, c, hw, kc4, acc);

    bf16x4 o;
#pragma unroll
    for (int j = 0; j < 4; j++) o[j] = (__bf16)acc[j];
    G[v] = o;
}

// ---------------- Pass 3: h/w bilinear + bias ----------------
__global__ __launch_bounds__(256)
void finalk(const bf16x4* __restrict__ G, const float* __restrict__ coor_h,
            const float* __restrict__ coor_w, const float* __restrict__ lin_b,
            float4* __restrict__ out)
{
    int v   = blockIdx.x * 256 + threadIdx.x;   // enumerates [nt][h][w][kc4]
    int kc4 = v & 127;
    int w   = (v >> 7) & 63;
    int r   = v >> 13;
    int h   = r % 36;
    int nt  = r / 36;                            // < 24
    int n   = nt / 12;

    float ch = coor_h[n * 36 + h];
    float cw = coor_w[n * 64 + w];

    // h axis: S = 9
    float xh  = (ch + 1.0f) * 0.5f * 8.0f;
    float xh0 = fminf(fmaxf(floorf(xh), 0.0f), 8.0f);
    int   h0  = (int)xh0;
    int   h1  = (h0 + 1 < 8) ? (h0 + 1) : 8;
    float fh  = xh - xh0;
    // w axis: S = 16
    float xw  = (cw + 1.0f) * 0.5f * 15.0f;
    float xw0 = fminf(fmaxf(floorf(xw), 0.0f), 15.0f);
    int   w0  = (int)xw0;
    int   w1  = (w0 + 1 < 15) ? (w0 + 1) : 15;
    float fw  = xw - xw0;

    int base = nt * 18432 + kc4;                 // nt*9*16*128, bf16x4 units
    bf16x4 g00 = G[base + (h0 * 16 + w0) * 128];
    bf16x4 g01 = G[base + (h0 * 16 + w1) * 128];
    bf16x4 g10 = G[base + (h1 * 16 + w0) * 128];
    bf16x4 g11 = G[base + (h1 * 16 + w1) * 128];

    float4 b = ((const float4*)lin_b)[kc4 & 31];
    float ofw = 1.0f - fw, ofh = 1.0f - fh;

    float4 o;
    o.x = ((float)g00[0] * ofw + (float)g01[0] * fw) * ofh + ((float)g10[0] * ofw + (float)g11[0] * fw) * fh + b.x;
    o.y = ((float)g00[1] * ofw + (float)g01[1] * fw) * ofh + ((float)g10[1] * ofw + (float)g11[1] * fw) * fh + b.y;
    o.z = ((float)g00[2] * ofw + (float)g01[2] * fw) * ofh + ((float)g10[2] * ofw + (float)g11[2] * fw) * fh + b.z;
    o.w = ((float)g00[3] * ofw + (float)g01[3] * fw) * ofh + ((float)g10[3] * ofw + (float)g11[3] * fw) * fh + b.w;
    out[v] = o;
}

extern "C" void kernel_launch(void* const* d_in, const int* in_sizes, int n_in,
                              void* d_out, int out_size, void* d_ws, size_t ws_size,
                              hipStream_t stream)
{
    const float* coor_t = (const float*)d_in[0];
    const float* coor_h = (const float*)d_in[1];
    const float* coor_w = (const float*)d_in[2];
    const float* g0     = (const float*)d_in[3];
    const float* g1     = (const float*)d_in[4];
    const float* g2     = (const float*)d_in[5];
    const float* lin_w  = (const float*)d_in[6];
    const float* lin_b  = (const float*)d_in[7];
    float* out = (float*)d_out;

    // workspace layout (bytes), all 16B-aligned; total 34,504,704 B
    char* ws = (char*)d_ws;
    __bf16* P0 = (__bf16*)(ws + 0);          // 69120*128 bf16 = 17,694,720 B
    __bf16* P1 = (__bf16*)(ws + 17694720);   // 34560*128 bf16 =  8,847,360 B
    __bf16* P2 = (__bf16*)(ws + 26542080);   // 17280*128 bf16 =  4,423,680 B
    __bf16* G  = (__bf16*)(ws + 30965760);   // 24*9*16*512 bf16 = 3,538,944 B

    // Pass 1: one merged launch for all three projection GEMMs (dead-slice skip)
    proj_gemm_all<<<945, 256, 0, stream>>>(g0, g1, g2, lin_w, coor_t, P0, P1, P2);

    // Pass 2: t-interp + sum grids -> merged G (3.5 MB, L2/L3-resident)
    tmix<<<1728, 256, 0, stream>>>((const bf16x4*)P0, (const bf16x4*)P1,
                                   (const bf16x4*)P2, coor_t, (bf16x4*)G);

    // Pass 3: h/w bilinear + bias -> f32 output (113 MB write)
    finalk<<<27648, 256, 0, stream>>>((const bf16x4*)G, coor_h, coor_w, lin_b,
                                      (float4*)out);
}

// Round 4
// 186.047 us; speedup vs baseline: 1.0367x; 1.0367x over previous
//
#include <hip/hip_runtime.h>

typedef __bf16 bf16x8 __attribute__((ext_vector_type(8)));
typedef __bf16 bf16x4 __attribute__((ext_vector_type(4)));
typedef float  f32x4  __attribute__((ext_vector_type(4)));

__device__ __forceinline__ bf16x8 pack8(float4 a, float4 b) {
    bf16x8 r;
    r[0] = (__bf16)a.x; r[1] = (__bf16)a.y; r[2] = (__bf16)a.z; r[3] = (__bf16)a.w;
    r[4] = (__bf16)b.x; r[5] = (__bf16)b.y; r[6] = (__bf16)b.z; r[7] = (__bf16)b.w;
    return r;
}

// ---------------- Pass 1 (fused): t-interp + projection GEMM -> G ----------------
// Virtual A matrix: rows = [nt(24)][hw(144)][k(4)] = 13824, cols = 448 (concat of
// grid channels). A[row, :] = (1-ft)*grid[i0-slice] + ft*grid[i1-slice], computed
// during LDS staging. G (13824,128) bf16 = A @ lin_w^T.
// Block = 64 rows (one nt per block since 576 rows/nt = 9 * 64), N = 128, K = 448.
// 4 waves: each owns one 16-row tile x 8 col-tiles (16x16 MFMA).
__global__ __launch_bounds__(256)
void gemmG(const float* __restrict__ g0, const float* __restrict__ g1,
           const float* __restrict__ g2, const float* __restrict__ W,
           const float* __restrict__ coor_t, __bf16* __restrict__ G)
{
    __shared__ __bf16 As[64][40];    // [row][k]  pad 32->40
    __shared__ __bf16 Bs[128][40];   // [col][k]

    const int m0 = blockIdx.x * 64;          // 216 blocks
    const int nt = m0 / 576;                 // uniform per block
    const float c = coor_t[nt];

    const int tid  = threadIdx.x;
    const int wid  = tid >> 6;
    const int lane = tid & 63;
    const int lrow = lane & 15;
    const int lk   = (lane >> 4) * 8;

    // A-staging role: srow 0..63 rows, q 0..3 -> 8 channels each
    const int srow = tid >> 2;
    const int q    = tid & 3;
    const int rem  = (m0 % 576) + srow;      // row within this nt
    const int hw   = rem >> 2;               // node index within slice (0..143)
    const int kp   = rem & 3;                // K_PROD index

    // B-staging role: col 0..127, half 0..1 -> 16 channels each
    const int bcol = tid >> 1;
    const int half = tid & 1;

    f32x4 acc[8];
#pragma unroll
    for (int ct = 0; ct < 8; ct++) acc[ct] = f32x4{0.f, 0.f, 0.f, 0.f};

    for (int k0 = 0; k0 < 448; k0 += 32) {
        // grid selection (uniform per K-step; boundaries 64/192 are multiples of 32)
        const float* gp; int off, Cg, Tg;
        if (k0 < 64)       { gp = g0; off = 0;   Cg = 64;  Tg = 120; }
        else if (k0 < 192) { gp = g1; off = 64;  Cg = 128; Tg = 60;  }
        else               { gp = g2; off = 192; Cg = 256; Tg = 30;  }

        // t-axis params (same math as reference _prep_axis)
        float x  = (c + 1.0f) * 0.5f * (float)(Tg - 1);
        float x0 = fminf(fmaxf(floorf(x), 0.0f), (float)(Tg - 1));
        int   i0 = (int)x0;
        int   i1 = (i0 + 1 < Tg - 1) ? (i0 + 1) : (Tg - 1);   // == min(i0+1, Tg-1)
        float ft = x - x0;
        float omf = 1.0f - ft;

        // stage A: lerp two t-slices, f32 -> bf16
        {
            const size_t ch = (size_t)(k0 - off) + q * 8;
            const float4* s0 = (const float4*)(gp + ((size_t)(i0 * 144 + hw) * 4 + kp) * Cg + ch);
            const float4* s1 = (const float4*)(gp + ((size_t)(i1 * 144 + hw) * 4 + kp) * Cg + ch);
            float4 a0 = s0[0], a1 = s0[1];
            float4 b0 = s1[0], b1 = s1[1];
            float4 v0, v1;
            v0.x = a0.x * omf + b0.x * ft; v0.y = a0.y * omf + b0.y * ft;
            v0.z = a0.z * omf + b0.z * ft; v0.w = a0.w * omf + b0.w * ft;
            v1.x = a1.x * omf + b1.x * ft; v1.y = a1.y * omf + b1.y * ft;
            v1.z = a1.z * omf + b1.z * ft; v1.w = a1.w * omf + b1.w * ft;
            *(bf16x8*)&As[srow][q * 8] = pack8(v0, v1);
        }
        // stage B: Bs[col][kk] = W[col][k0+kk]  (k0 IS the lin_w column offset)
        {
            const float4* src = (const float4*)(W + (size_t)bcol * 448 + k0 + half * 16);
            float4 f0 = src[0], f1 = src[1], f2 = src[2], f3 = src[3];
            *(bf16x8*)&Bs[bcol][half * 16 + 0] = pack8(f0, f1);
            *(bf16x8*)&Bs[bcol][half * 16 + 8] = pack8(f2, f3);
        }
        __syncthreads();

        bf16x8 a = *(const bf16x8*)&As[wid * 16 + lrow][lk];
        bf16x8 bfrag[8];
#pragma unroll
        for (int ct = 0; ct < 8; ct++)
            bfrag[ct] = *(const bf16x8*)&Bs[ct * 16 + lrow][lk];
#pragma unroll
        for (int ct = 0; ct < 8; ct++)
            acc[ct] = __builtin_amdgcn_mfma_f32_16x16x32_bf16(a, bfrag[ct], acc[ct], 0, 0, 0);
        __syncthreads();
    }

    // epilogue: D layout col = lane&15, row = (lane>>4)*4 + j  [verified m89/m91]
    const int r0 = m0 + wid * 16 + (lane >> 4) * 4;
#pragma unroll
    for (int ct = 0; ct < 8; ct++) {
        const int col = ct * 16 + lrow;
#pragma unroll
        for (int j = 0; j < 4; j++)
            G[(size_t)(r0 + j) * 128 + col] = (__bf16)acc[ct][j];
    }
}

// ---------------- Pass 2: h/w bilinear + bias ----------------
__global__ __launch_bounds__(256)
void finalk(const bf16x4* __restrict__ G, const float* __restrict__ coor_h,
            const float* __restrict__ coor_w, const float* __restrict__ lin_b,
            f32x4* __restrict__ out)
{
    int v   = blockIdx.x * 256 + threadIdx.x;   // enumerates [nt][h][w][kc4]
    int kc4 = v & 127;
    int w   = (v >> 7) & 63;
    int r   = v >> 13;
    int h   = r % 36;
    int nt  = r / 36;                            // < 24
    int n   = nt / 12;

    float ch = coor_h[n * 36 + h];
    float cw = coor_w[n * 64 + w];

    // h axis: S = 9
    float xh  = (ch + 1.0f) * 0.5f * 8.0f;
    float xh0 = fminf(fmaxf(floorf(xh), 0.0f), 8.0f);
    int   h0  = (int)xh0;
    int   h1  = (h0 + 1 < 8) ? (h0 + 1) : 8;
    float fh  = xh - xh0;
    // w axis: S = 16
    float xw  = (cw + 1.0f) * 0.5f * 15.0f;
    float xw0 = fminf(fmaxf(floorf(xw), 0.0f), 15.0f);
    int   w0  = (int)xw0;
    int   w1  = (w0 + 1 < 15) ? (w0 + 1) : 15;
    float fw  = xw - xw0;

    int base = nt * 18432 + kc4;                 // nt*9*16*128, bf16x4 units
    bf16x4 g00 = G[base + (h0 * 16 + w0) * 128];
    bf16x4 g01 = G[base + (h0 * 16 + w1) * 128];
    bf16x4 g10 = G[base + (h1 * 16 + w0) * 128];
    bf16x4 g11 = G[base + (h1 * 16 + w1) * 128];

    float4 b = ((const float4*)lin_b)[kc4 & 31];
    float ofw = 1.0f - fw, ofh = 1.0f - fh;

    f32x4 o;
    o[0] = ((float)g00[0] * ofw + (float)g01[0] * fw) * ofh + ((float)g10[0] * ofw + (float)g11[0] * fw) * fh + b.x;
    o[1] = ((float)g00[1] * ofw + (float)g01[1] * fw) * ofh + ((float)g10[1] * ofw + (float)g11[1] * fw) * fh + b.y;
    o[2] = ((float)g00[2] * ofw + (float)g01[2] * fw) * ofh + ((float)g10[2] * ofw + (float)g11[2] * fw) * fh + b.z;
    o[3] = ((float)g00[3] * ofw + (float)g01[3] * fw) * ofh + ((float)g10[3] * ofw + (float)g11[3] * fw) * fh + b.w;
    __builtin_nontemporal_store(o, &out[v]);     // 113 MB stream; keep L2 for G
}

extern "C" void kernel_launch(void* const* d_in, const int* in_sizes, int n_in,
                              void* d_out, int out_size, void* d_ws, size_t ws_size,
                              hipStream_t stream)
{
    const float* coor_t = (const float*)d_in[0];
    const float* coor_h = (const float*)d_in[1];
    const float* coor_w = (const float*)d_in[2];
    const float* g0     = (const float*)d_in[3];
    const float* g1     = (const float*)d_in[4];
    const float* g2     = (const float*)d_in[5];
    const float* lin_w  = (const float*)d_in[6];
    const float* lin_b  = (const float*)d_in[7];

    // workspace: only merged grid G  (13824 * 128 bf16 = 3,538,944 B)
    __bf16* G = (__bf16*)d_ws;

    // Pass 1: fused t-interp + projection GEMM (reads only needed t-slices)
    gemmG<<<216, 256, 0, stream>>>(g0, g1, g2, lin_w, coor_t, G);

    // Pass 2: h/w bilinear + bias -> f32 output (113 MB write)
    finalk<<<27648, 256, 0, stream>>>((const bf16x4*)G, coor_h, coor_w, lin_b,
                                      (f32x4*)d_out);
}

// Round 10
// 185.218 us; speedup vs baseline: 1.0414x; 1.0045x over previous
//
#include <hip/hip_runtime.h>

typedef __bf16 bf16x8 __attribute__((ext_vector_type(8)));
typedef __bf16 bf16x4 __attribute__((ext_vector_type(4)));
typedef float  f32x4  __attribute__((ext_vector_type(4)));

__device__ __forceinline__ bf16x8 pack8(float4 a, float4 b) {
    bf16x8 r;
    r[0] = (__bf16)a.x; r[1] = (__bf16)a.y; r[2] = (__bf16)a.z; r[3] = (__bf16)a.w;
    r[4] = (__bf16)b.x; r[5] = (__bf16)b.y; r[6] = (__bf16)b.z; r[7] = (__bf16)b.w;
    return r;
}

// ---------------- Pass 1 (fused): t-interp + projection GEMM -> G ----------------
// Virtual A (13824 x 448): rows [nt(24)][hw(144)][kp(4)], A[row,:] = t-lerp of two
// grid slices, computed during staging. G (13824,128) bf16 = A @ lin_w^T.
// Block = 64 rows (one nt per block), N = 128, K = 448 in 7 chunks of 64.
// 1-deep register prefetch: chunk k+1's global loads issue before chunk k's MFMA.
__global__ __launch_bounds__(256)
void gemmG(const float* __restrict__ g0, const float* __restrict__ g1,
           const float* __restrict__ g2, const float* __restrict__ W,
           const float* __restrict__ coor_t, __bf16* __restrict__ G)
{
    __shared__ __bf16 As[64][72];    // 9.2 KB  (72 pad: 144B row stride, 2-way free)
    __shared__ __bf16 Bs[128][72];   // 18.4 KB

    const int m0 = blockIdx.x * 64;          // 216 blocks
    const int nt = m0 / 576;
    const float c = coor_t[nt];

    const int tid  = threadIdx.x;
    const int wid  = tid >> 6;
    const int lane = tid & 63;
    const int lrow = lane & 15;
    const int lk   = (lane >> 4) * 8;

    // A-staging role: 64 rows x 4 threads; thread covers 16 channels
    const int srow = tid >> 2;
    const int q    = tid & 3;
    const int rem  = (m0 % 576) + srow;
    const int hw   = rem >> 2;
    const int kp   = rem & 3;
    // B-staging role: 128 cols x 2 threads; thread covers 32 channels
    const int bcol = tid >> 1;
    const int half = tid & 1;

    // t-axis params per grid (scalar; same math as reference _prep_axis)
    int i0_0, i1_0, i0_1, i1_1, i0_2, i1_2;
    float ft_0, ft_1, ft_2;
    {
        float x, x0;
        x = (c + 1.0f) * 0.5f * 119.0f;
        x0 = fminf(fmaxf(floorf(x), 0.0f), 119.0f);
        i0_0 = (int)x0; i1_0 = (i0_0 + 1 < 119) ? i0_0 + 1 : 119; ft_0 = x - x0;
        x = (c + 1.0f) * 0.5f * 59.0f;
        x0 = fminf(fmaxf(floorf(x), 0.0f), 59.0f);
        i0_1 = (int)x0; i1_1 = (i0_1 + 1 < 59) ? i0_1 + 1 : 59; ft_1 = x - x0;
        x = (c + 1.0f) * 0.5f * 29.0f;
        x0 = fminf(fmaxf(floorf(x), 0.0f), 29.0f);
        i0_2 = (int)x0; i1_2 = (i0_2 + 1 < 29) ? i0_2 + 1 : 29; ft_2 = x - x0;
    }

    f32x4 acc[8];
#pragma unroll
    for (int ct = 0; ct < 8; ct++) acc[ct] = f32x4{0.f, 0.f, 0.f, 0.f};

    float4 ra0[4], ra1[4], rb[8];
    float  ft_s = 0.f;

    auto load_chunk = [&](int kk) {
        const int gi = (kk == 0) ? 0 : ((kk < 3) ? 1 : 2);
        const float* gp = (gi == 0) ? g0 : ((gi == 1) ? g1 : g2);
        const int off = (gi == 0) ? 0 : ((gi == 1) ? 64 : 192);
        const int Cg  = (gi == 0) ? 64 : ((gi == 1) ? 128 : 256);
        const int i0  = (gi == 0) ? i0_0 : ((gi == 1) ? i0_1 : i0_2);
        const int i1  = (gi == 0) ? i1_0 : ((gi == 1) ? i1_1 : i1_2);
        ft_s          = (gi == 0) ? ft_0 : ((gi == 1) ? ft_1 : ft_2);
        const size_t ch = (size_t)(kk * 64 - off) + q * 16;
        const float4* s0 = (const float4*)(gp + ((size_t)(i0 * 144 + hw) * 4 + kp) * Cg + ch);
        const float4* s1 = (const float4*)(gp + ((size_t)(i1 * 144 + hw) * 4 + kp) * Cg + ch);
#pragma unroll
        for (int j = 0; j < 4; j++) { ra0[j] = s0[j]; ra1[j] = s1[j]; }
        const float4* sb = (const float4*)(W + (size_t)bcol * 448 + kk * 64 + half * 32);
#pragma unroll
        for (int j = 0; j < 8; j++) rb[j] = sb[j];
    };

    load_chunk(0);

#pragma unroll
    for (int kc = 0; kc < 7; kc++) {
        if (kc) __syncthreads();             // prior compute done before LDS overwrite
        // lerp + pack + ds_write from staged regs (vmcnt wait lands here)
        {
            const float f = ft_s, omf = 1.0f - f;
            float4 v[4];
#pragma unroll
            for (int j = 0; j < 4; j++) {
                v[j].x = ra0[j].x * omf + ra1[j].x * f;
                v[j].y = ra0[j].y * omf + ra1[j].y * f;
                v[j].z = ra0[j].z * omf + ra1[j].z * f;
                v[j].w = ra0[j].w * omf + ra1[j].w * f;
            }
            *(bf16x8*)&As[srow][q * 16 + 0] = pack8(v[0], v[1]);
            *(bf16x8*)&As[srow][q * 16 + 8] = pack8(v[2], v[3]);
            *(bf16x8*)&Bs[bcol][half * 32 + 0]  = pack8(rb[0], rb[1]);
            *(bf16x8*)&Bs[bcol][half * 32 + 8]  = pack8(rb[2], rb[3]);
            *(bf16x8*)&Bs[bcol][half * 32 + 16] = pack8(rb[4], rb[5]);
            *(bf16x8*)&Bs[bcol][half * 32 + 24] = pack8(rb[6], rb[7]);
        }
        __syncthreads();
        if (kc < 6) load_chunk(kc + 1);      // prefetch: latency hides under MFMA
#pragma unroll
        for (int sub = 0; sub < 2; sub++) {
            bf16x8 a = *(const bf16x8*)&As[wid * 16 + lrow][sub * 32 + lk];
            bf16x8 bfrag[8];
#pragma unroll
            for (int ct = 0; ct < 8; ct++)
                bfrag[ct] = *(const bf16x8*)&Bs[ct * 16 + lrow][sub * 32 + lk];
#pragma unroll
            for (int ct = 0; ct < 8; ct++)
                acc[ct] = __builtin_amdgcn_mfma_f32_16x16x32_bf16(a, bfrag[ct], acc[ct], 0, 0, 0);
        }
    }

    // epilogue: D layout col = lane&15, row = (lane>>4)*4 + j  [verified m89/m91]
    const int r0 = m0 + wid * 16 + (lane >> 4) * 4;
#pragma unroll
    for (int ct = 0; ct < 8; ct++) {
        const int col = ct * 16 + lrow;
#pragma unroll
        for (int j = 0; j < 4; j++)
            G[(size_t)(r0 + j) * 128 + col] = (__bf16)acc[ct][j];
    }
}

// ---------------- Pass 2: h/w bilinear + bias ----------------
// One block per (nt,h): stage the two needed G h-rows (2 x 16 KB) in LDS, then
// 32 iterations of LDS-corner bilinear + nontemporal f32 output stream.
__global__ __launch_bounds__(256)
void finalk(const __bf16* __restrict__ G, const float* __restrict__ coor_h,
            const float* __restrict__ coor_w, const float* __restrict__ lin_b,
            f32x4* __restrict__ out)
{
    __shared__ __bf16 Ls[2][8192];   // [h-row][w'(16)*512ch] = 32 KB

    const int blk = blockIdx.x;      // [nt(24)][h(36)] = 864 blocks
    const int h   = blk % 36;
    const int nt  = blk / 36;
    const int n   = nt / 12;
    const int tid = threadIdx.x;

    const float chv = coor_h[n * 36 + h];
    const float xh  = (chv + 1.0f) * 0.5f * 8.0f;
    const float xh0 = fminf(fmaxf(floorf(xh), 0.0f), 8.0f);
    const int   h0  = (int)xh0;
    const int   h1  = (h0 + 1 < 8) ? h0 + 1 : 8;
    const float fh  = xh - xh0, ofh = 1.0f - fh;

    // stage rows h0,h1 of G[nt]  (G f32x4 units: nt*9216 + h'*1024)
    {
        const f32x4* r0 = (const f32x4*)G + (size_t)nt * 9216 + h0 * 1024;
        const f32x4* r1 = (const f32x4*)G + (size_t)nt * 9216 + h1 * 1024;
        f32x4* L0 = (f32x4*)&Ls[0][0];
        f32x4* L1 = (f32x4*)&Ls[1][0];
#pragma unroll
        for (int j = 0; j < 4; j++) {
            L0[j * 256 + tid] = r0[j * 256 + tid];
            L1[j * 256 + tid] = r1[j * 256 + tid];
        }
    }
    __syncthreads();

    const bf16x4* L0v = (const bf16x4*)&Ls[0][0];
    const bf16x4* L1v = (const bf16x4*)&Ls[1][0];
    const size_t obase = (size_t)blk * 8192;

#pragma unroll 4
    for (int it = 0; it < 32; ++it) {
        const int idx = it * 256 + tid;      // [w(64)][kc4(128)]
        const int w   = idx >> 7;
        const int kc4 = idx & 127;

        const float cwv = coor_w[n * 64 + w];
        const float xw  = (cwv + 1.0f) * 0.5f * 15.0f;
        const float xw0 = fminf(fmaxf(floorf(xw), 0.0f), 15.0f);
        const int   w0  = (int)xw0;
        const int   w1  = (w0 + 1 < 15) ? w0 + 1 : 15;
        const float fw  = xw - xw0, ofw = 1.0f - fw;

        const bf16x4 g00 = L0v[w0 * 128 + kc4];
        const bf16x4 g01 = L0v[w1 * 128 + kc4];
        const bf16x4 g10 = L1v[w0 * 128 + kc4];
        const bf16x4 g11 = L1v[w1 * 128 + kc4];
        const float4 b = ((const float4*)lin_b)[kc4 & 31];

        f32x4 o;
        o[0] = ((float)g00[0] * ofw + (float)g01[0] * fw) * ofh + ((float)g10[0] * ofw + (float)g11[0] * fw) * fh + b.x;
        o[1] = ((float)g00[1] * ofw + (float)g01[1] * fw) * ofh + ((float)g10[1] * ofw + (float)g11[1] * fw) * fh + b.y;
        o[2] = ((float)g00[2] * ofw + (float)g01[2] * fw) * ofh + ((float)g10[2] * ofw + (float)g11[2] * fw) * fh + b.z;
        o[3] = ((float)g00[3] * ofw + (float)g01[3] * fw) * ofh + ((float)g10[3] * ofw + (float)g11[3] * fw) * fh + b.w;
        __builtin_nontemporal_store(o, &out[obase + idx]);   // 113 MB stream
    }
}

extern "C" void kernel_launch(void* const* d_in, const int* in_sizes, int n_in,
                              void* d_out, int out_size, void* d_ws, size_t ws_size,
                              hipStream_t stream)
{
    const float* coor_t = (const float*)d_in[0];
    const float* coor_h = (const float*)d_in[1];
    const float* coor_w = (const float*)d_in[2];
    const float* g0     = (const float*)d_in[3];
    const float* g1     = (const float*)d_in[4];
    const float* g2     = (const float*)d_in[5];
    const float* lin_w  = (const float*)d_in[6];
    const float* lin_b  = (const float*)d_in[7];

    // workspace: only merged grid G  (13824 * 128 bf16 = 3,538,944 B)
    __bf16* G = (__bf16*)d_ws;

    gemmG<<<216, 256, 0, stream>>>(g0, g1, g2, lin_w, coor_t, G);
    finalk<<<864, 256, 0, stream>>>(G, coor_h, coor_w, lin_b, (f32x4*)d_out);
}